// Round 1
// baseline (612.972 us; speedup 1.0000x reference)
//
#include <hip/hip_runtime.h>
#include <hip/hip_bf16.h>

#define N_NODES 50000
#define N_EDGES 250000
#define DIN_ 256
#define DOUT_ 256
#define OH_ 16
#define KF_ 288   // 256 (h) + 16 (degrees) + 16 zero-pad -> 9 K-steps of 32

typedef short short8 __attribute__((ext_vector_type(8)));
typedef float f32x4 __attribute__((ext_vector_type(4)));

__device__ __forceinline__ unsigned short f2bf(float f) {
    unsigned u = __builtin_bit_cast(unsigned, f);
    return (unsigned short)((u + 0x7fffu + ((u >> 16) & 1u)) >> 16);
}

__device__ __forceinline__ uint4 pack8(float f0, float f1, float f2, float f3,
                                       float f4, float f5, float f6, float f7) {
    uint4 u;
    u.x = (unsigned)f2bf(f0) | ((unsigned)f2bf(f1) << 16);
    u.y = (unsigned)f2bf(f2) | ((unsigned)f2bf(f3) << 16);
    u.z = (unsigned)f2bf(f4) | ((unsigned)f2bf(f5) << 16);
    u.w = (unsigned)f2bf(f6) | ((unsigned)f2bf(f7) << 16);
    return u;
}

// Build transposed bf16 weights in workspace:
//   WT_lin[n][k], n<256, k<256
//   WT_k[n][k],   n<256, k<288 (k>=272 zero)
__global__ void prep_kernel(const float* __restrict__ W_lin,
                            const float* __restrict__ W_k0,
                            const float* __restrict__ W_k1,
                            unsigned short* __restrict__ WT_lin,
                            unsigned short* __restrict__ WT_k0,
                            unsigned short* __restrict__ WT_k1) {
    int idx = blockIdx.x * 256 + threadIdx.x;
    if (idx < DOUT_ * DIN_) {
        int n = idx >> 8, k = idx & 255;
        WT_lin[idx] = f2bf(W_lin[k * DOUT_ + n]);
    }
    if (idx < DOUT_ * KF_) {
        int n = idx / KF_, k = idx - n * KF_;
        float v0 = 0.f, v1 = 0.f;
        if (k < DIN_ + OH_) {
            v0 = W_k0[k * DOUT_ + n];
            v1 = W_k1[k * DOUT_ + n];
        }
        WT_k0[idx] = f2bf(v0);
        WT_k1[idx] = f2bf(v1);
    }
}

// h3 = h @ W_lin + b_lin   (writes all of d_out)
__global__ __launch_bounds__(256) void main_gemm(const float* __restrict__ h,
                                                 const unsigned short* __restrict__ WT,
                                                 const float* __restrict__ bias,
                                                 float* __restrict__ out) {
    __shared__ unsigned short Alds[64][40];   // stride 40 bf16 = 80B (16B aligned, 2-way banks)
    __shared__ unsigned short Blds[256][40];
    __shared__ float bias_lds[256];
    int tid = threadIdx.x;
    int wave = tid >> 6, lane = tid & 63;
    int row0 = blockIdx.x * 64;
    bias_lds[tid] = bias[tid];

    f32x4 acc[16];
#pragma unroll
    for (int j = 0; j < 16; ++j) acc[j] = (f32x4)(0.f);

    int r = tid >> 2, q = tid & 3;
    int grow = row0 + r;
    if (grow >= N_NODES) grow = N_NODES - 1;
    const float* hrow = h + (size_t)grow * DIN_;
    __syncthreads();

    for (int kk = 0; kk < 8; ++kk) {
        const float4* s4 = (const float4*)(hrow + kk * 32 + q * 8);
        float4 a = s4[0], b4 = s4[1];
        *(uint4*)&Alds[r][q * 8] = pack8(a.x, a.y, a.z, a.w, b4.x, b4.y, b4.z, b4.w);
        const uint4* ws = (const uint4*)(WT + tid * DIN_ + kk * 32);
        uint4 w0 = ws[0], w1 = ws[1], w2 = ws[2], w3 = ws[3];
        uint4* bd = (uint4*)&Blds[tid][0];
        bd[0] = w0; bd[1] = w1; bd[2] = w2; bd[3] = w3;
        __syncthreads();
        short8 af = *(const short8*)&Alds[wave * 16 + (lane & 15)][(lane >> 4) * 8];
#pragma unroll
        for (int j = 0; j < 16; ++j) {
            short8 bf = *(const short8*)&Blds[j * 16 + (lane & 15)][(lane >> 4) * 8];
            acc[j] = __builtin_amdgcn_mfma_f32_16x16x32_bf16(af, bf, acc[j], 0, 0, 0);
        }
        __syncthreads();
    }

    int rbase = row0 + wave * 16 + ((lane >> 4) << 2);
#pragma unroll
    for (int j = 0; j < 16; ++j) {
        int n = j * 16 + (lane & 15);
        float bv = bias_lds[n];
#pragma unroll
        for (int i = 0; i < 4; ++i) {
            int rr = rbase + i;
            if (rr < N_NODES) out[(size_t)rr * DOUT_ + n] = acc[j][i] + bv;
        }
    }
}

// One key term: out[scatter[e]] += (1+eps) * sigmoid(A0@W+b) * sigmoid(A1@W+b)
// A_t[e] = [h[pairs[t][e]], degrees[t][e]]  (K = 256+16, padded to 288)
__global__ __launch_bounds__(256) void edge_gemm(const float* __restrict__ h,
                                                 const int* __restrict__ pairs,     // [2][E]
                                                 const float* __restrict__ degrees, // [2][E][16]
                                                 const int* __restrict__ scatter,   // [E]
                                                 const unsigned short* __restrict__ WT, // [256][288]
                                                 const float* __restrict__ bias,
                                                 const float* __restrict__ eps,
                                                 float* __restrict__ out) {
    __shared__ unsigned short Alds[2][64][40];
    __shared__ unsigned short Blds[256][40];
    __shared__ int plds[2][64];
    __shared__ int slds[64];
    __shared__ float bias_lds[256];
    int tid = threadIdx.x;
    int wave = tid >> 6, lane = tid & 63;
    int e0 = blockIdx.x * 64;
    bias_lds[tid] = bias[tid];
    if (tid < 128) {
        int t = tid >> 6, rr = tid & 63;
        int e = e0 + rr; if (e >= N_EDGES) e = N_EDGES - 1;
        plds[t][rr] = pairs[t * N_EDGES + e];
    } else if (tid < 192) {
        int rr = tid - 128;
        int e = e0 + rr; if (e >= N_EDGES) e = N_EDGES - 1;
        slds[rr] = scatter[e];
    }

    f32x4 acc0[16], acc1[16];
#pragma unroll
    for (int j = 0; j < 16; ++j) { acc0[j] = (f32x4)(0.f); acc1[j] = (f32x4)(0.f); }

    int r = tid >> 2, q = tid & 3;
    int e = e0 + r;
    int ec = e < N_EDGES ? e : N_EDGES - 1;
    __syncthreads();

    for (int kk = 0; kk < 9; ++kk) {
        if (kk < 8) {
#pragma unroll
            for (int t = 0; t < 2; ++t) {
                const float4* s4 = (const float4*)(h + (size_t)plds[t][r] * DIN_ + kk * 32 + q * 8);
                float4 a = s4[0], b4 = s4[1];
                *(uint4*)&Alds[t][r][q * 8] = pack8(a.x, a.y, a.z, a.w, b4.x, b4.y, b4.z, b4.w);
            }
        } else {
            // k 256..271 = degrees, 272..287 = 0
#pragma unroll
            for (int t = 0; t < 2; ++t) {
                uint4 u = make_uint4(0u, 0u, 0u, 0u);
                if (q < 2) {
                    const float4* s4 = (const float4*)(degrees + ((size_t)t * N_EDGES + ec) * OH_ + q * 8);
                    float4 a = s4[0], b4 = s4[1];
                    u = pack8(a.x, a.y, a.z, a.w, b4.x, b4.y, b4.z, b4.w);
                }
                *(uint4*)&Alds[t][r][q * 8] = u;
            }
        }
        const uint4* ws = (const uint4*)(WT + tid * KF_ + kk * 32);
        uint4 w0 = ws[0], w1 = ws[1], w2 = ws[2], w3 = ws[3];
        uint4* bd = (uint4*)&Blds[tid][0];
        bd[0] = w0; bd[1] = w1; bd[2] = w2; bd[3] = w3;
        __syncthreads();
        short8 a0f = *(const short8*)&Alds[0][wave * 16 + (lane & 15)][(lane >> 4) * 8];
        short8 a1f = *(const short8*)&Alds[1][wave * 16 + (lane & 15)][(lane >> 4) * 8];
#pragma unroll
        for (int j = 0; j < 16; ++j) {
            short8 bf = *(const short8*)&Blds[j * 16 + (lane & 15)][(lane >> 4) * 8];
            acc0[j] = __builtin_amdgcn_mfma_f32_16x16x32_bf16(a0f, bf, acc0[j], 0, 0, 0);
            acc1[j] = __builtin_amdgcn_mfma_f32_16x16x32_bf16(a1f, bf, acc1[j], 0, 0, 0);
        }
        __syncthreads();
    }

    float epv = 1.0f + eps[0];
    int rloc = wave * 16 + ((lane >> 4) << 2);
#pragma unroll
    for (int j = 0; j < 16; ++j) {
        int n = j * 16 + (lane & 15);
        float bv = bias_lds[n];
#pragma unroll
        for (int i = 0; i < 4; ++i) {
            int ee = e0 + rloc + i;
            if (ee < N_EDGES) {
                float s0 = 1.0f / (1.0f + __expf(-(acc0[j][i] + bv)));
                float s1 = 1.0f / (1.0f + __expf(-(acc1[j][i] + bv)));
                atomicAdd(&out[(size_t)slds[rloc + i] * DOUT_ + n], epv * s0 * s1);
            }
        }
    }
}

extern "C" void kernel_launch(void* const* d_in, const int* in_sizes, int n_in,
                              void* d_out, int out_size, void* d_ws, size_t ws_size,
                              hipStream_t stream) {
    const float* h        = (const float*)d_in[0];
    const int*   pairs_k0 = (const int*)d_in[1];
    const int*   pairs_k1 = (const int*)d_in[2];
    const float* deg_k0   = (const float*)d_in[3];
    const float* deg_k1   = (const float*)d_in[4];
    const int*   sc_k0    = (const int*)d_in[5];
    const int*   sc_k1    = (const int*)d_in[6];
    const float* W_lin    = (const float*)d_in[7];
    const float* b_lin    = (const float*)d_in[8];
    const float* W_k0     = (const float*)d_in[9];
    const float* b_k0     = (const float*)d_in[10];
    const float* W_k1     = (const float*)d_in[11];
    const float* b_k1     = (const float*)d_in[12];
    const float* eps_k0   = (const float*)d_in[13];
    const float* eps_k1   = (const float*)d_in[14];
    float* out = (float*)d_out;

    size_t need = (size_t)(DOUT_ * DIN_ + 2 * DOUT_ * KF_) * sizeof(unsigned short);
    if (ws_size < need) return;  // workspace too small — fail loudly in validation
    unsigned short* WT_lin = (unsigned short*)d_ws;
    unsigned short* WT_k0  = WT_lin + DOUT_ * DIN_;
    unsigned short* WT_k1  = WT_k0 + DOUT_ * KF_;

    prep_kernel<<<(DOUT_ * KF_ + 255) / 256, 256, 0, stream>>>(W_lin, W_k0, W_k1,
                                                               WT_lin, WT_k0, WT_k1);
    main_gemm<<<(N_NODES + 63) / 64, 256, 0, stream>>>(h, WT_lin, b_lin, out);
    edge_gemm<<<(N_EDGES + 63) / 64, 256, 0, stream>>>(h, pairs_k0, deg_k0, sc_k0,
                                                       WT_k0, b_k0, eps_k0, out);
    edge_gemm<<<(N_EDGES + 63) / 64, 256, 0, stream>>>(h, pairs_k1, deg_k1, sc_k1,
                                                       WT_k1, b_k1, eps_k1, out);
}

// Round 2
// 527.082 us; speedup vs baseline: 1.1630x; 1.1630x over previous
//
#include <hip/hip_runtime.h>
#include <hip/hip_bf16.h>

#define N_NODES 50000
#define N_EDGES 250000
#define DIN_ 256
#define DOUT_ 256
#define OH_ 16
#define KF_ 288   // 256 (h) + 16 (degrees) + 16 zero-pad -> 9 K-steps of 32

typedef short short8 __attribute__((ext_vector_type(8)));
typedef float f32x4 __attribute__((ext_vector_type(4)));

__device__ __forceinline__ unsigned short f2bf(float f) {
    unsigned u = __builtin_bit_cast(unsigned, f);
    return (unsigned short)((u + 0x7fffu + ((u >> 16) & 1u)) >> 16);
}

__device__ __forceinline__ uint4 pack8(float f0, float f1, float f2, float f3,
                                       float f4, float f5, float f6, float f7) {
    uint4 u;
    u.x = (unsigned)f2bf(f0) | ((unsigned)f2bf(f1) << 16);
    u.y = (unsigned)f2bf(f2) | ((unsigned)f2bf(f3) << 16);
    u.z = (unsigned)f2bf(f4) | ((unsigned)f2bf(f5) << 16);
    u.w = (unsigned)f2bf(f6) | ((unsigned)f2bf(f7) << 16);
    return u;
}

// async global -> LDS, 16 bytes per lane (dest = wave-uniform base + lane*16)
__device__ __forceinline__ void gl_lds16(const void* g, void* l) {
    __builtin_amdgcn_global_load_lds(
        (const __attribute__((address_space(1))) unsigned int*)g,
        (__attribute__((address_space(3))) unsigned int*)l, 16, 0, 0);
}

// Build transposed bf16 weights in workspace:
//   WT_lin[n][k], n<256, k<256
//   WT_k[n][k],   n<256, k<288 (k>=272 zero)
__global__ void prep_weights(const float* __restrict__ W_lin,
                             const float* __restrict__ W_k0,
                             const float* __restrict__ W_k1,
                             unsigned short* __restrict__ WT_lin,
                             unsigned short* __restrict__ WT_k0,
                             unsigned short* __restrict__ WT_k1) {
    int idx = blockIdx.x * 256 + threadIdx.x;
    if (idx < DOUT_ * DIN_) {
        int n = idx >> 8, k = idx & 255;
        WT_lin[idx] = f2bf(W_lin[k * DOUT_ + n]);
    }
    if (idx < DOUT_ * KF_) {
        int n = idx / KF_, k = idx - n * KF_;
        float v0 = 0.f, v1 = 0.f;
        if (k < DIN_ + OH_) {
            v0 = W_k0[k * DOUT_ + n];
            v1 = W_k1[k * DOUT_ + n];
        }
        WT_k0[idx] = f2bf(v0);
        WT_k1[idx] = f2bf(v1);
    }
}

// h (f32) -> h_bf16, 8 elements per thread
__global__ void conv_h(const float* __restrict__ h, unsigned short* __restrict__ hbf) {
    int idx = blockIdx.x * 256 + threadIdx.x;   // 0 .. N*DIN/8-1 (exact)
    const float4* s = (const float4*)(h + (size_t)idx * 8);
    float4 a = s[0], b = s[1];
    ((uint4*)hbf)[idx] = pack8(a.x, a.y, a.z, a.w, b.x, b.y, b.z, b.w);
}

// h3 = h @ W_lin + b_lin   (writes all of d_out)
__global__ __launch_bounds__(256) void main_gemm(const unsigned short* __restrict__ hbf,
                                                 const unsigned short* __restrict__ WT,
                                                 const float* __restrict__ bias,
                                                 float* __restrict__ out) {
    __shared__ unsigned short Alds[2][64][32];    // 8 KB
    __shared__ unsigned short Blds[2][256][32];   // 32 KB
    __shared__ float bias_lds[256];
    int tid = threadIdx.x;
    int w = tid >> 6, ln = tid & 63, l15 = ln & 15;
    int row0 = blockIdx.x * 64;
    bias_lds[tid] = bias[tid];

    int ar = row0 + w * 16 + (ln >> 2);
    if (ar >= N_NODES) ar = N_NODES - 1;
    int qs = (ln & 3) ^ ((ln >> 3) & 3);                // source-side swizzle
    const unsigned short* asrc = hbf + (size_t)ar * DIN_ + qs * 8;
    int brow = w * 64;                                   // this wave's B rows base
    int swz = ((ln >> 4) ^ ((l15 >> 1) & 3)) * 8;        // read-side swizzle (ushorts)

    f32x4 acc[16];
#pragma unroll
    for (int j = 0; j < 16; ++j) acc[j] = (f32x4)(0.f);

    // prologue stage kk=0 into buf 0
    gl_lds16(asrc, &Alds[0][w * 16][0]);
#pragma unroll
    for (int i = 0; i < 4; ++i) {
        int n = brow + i * 16 + (ln >> 2);
        gl_lds16(WT + (size_t)n * DIN_ + qs * 8, &Blds[0][brow + i * 16][0]);
    }
    __syncthreads();

    int buf = 0;
    for (int kk = 0; kk < 8; ++kk) {
        if (kk < 7) {
            gl_lds16(asrc + (kk + 1) * 32, &Alds[buf ^ 1][w * 16][0]);
#pragma unroll
            for (int i = 0; i < 4; ++i) {
                int n = brow + i * 16 + (ln >> 2);
                gl_lds16(WT + (size_t)n * DIN_ + (kk + 1) * 32 + qs * 8,
                         &Blds[buf ^ 1][brow + i * 16][0]);
            }
        }
        short8 af = *(const short8*)&Alds[buf][w * 16 + l15][swz];
#pragma unroll
        for (int j = 0; j < 16; ++j) {
            short8 bf = *(const short8*)&Blds[buf][j * 16 + l15][swz];
            acc[j] = __builtin_amdgcn_mfma_f32_16x16x32_bf16(af, bf, acc[j], 0, 0, 0);
        }
        __syncthreads();
        buf ^= 1;
    }

    int rbase = row0 + w * 16 + ((ln >> 4) << 2);
#pragma unroll
    for (int j = 0; j < 16; ++j) {
        int n = j * 16 + l15;
        float bv = bias_lds[n];
#pragma unroll
        for (int i = 0; i < 4; ++i) {
            int rr = rbase + i;
            if (rr < N_NODES) out[(size_t)rr * DOUT_ + n] = acc[j][i] + bv;
        }
    }
}

// One key term: out[scatter[e]] += (1+eps) * sigmoid(A0@W+b) * sigmoid(A1@W+b)
__global__ __launch_bounds__(256) void edge_gemm(const unsigned short* __restrict__ hbf,
                                                 const int* __restrict__ pairs,     // [2][E]
                                                 const float* __restrict__ degrees, // [2][E][16]
                                                 const int* __restrict__ scatter,   // [E]
                                                 const unsigned short* __restrict__ WT, // [256][288]
                                                 const float* __restrict__ bias,
                                                 const float* __restrict__ eps,
                                                 float* __restrict__ out) {
    __shared__ unsigned short Alds[2][2][64][32];   // [buf][t][row][col] 16 KB
    __shared__ unsigned short Blds[2][256][32];     // 32 KB
    __shared__ float bias_lds[256];
    int tid = threadIdx.x;
    int w = tid >> 6, ln = tid & 63, l15 = ln & 15;
    int e0 = blockIdx.x * 64;
    bias_lds[tid] = bias[tid];

    int er = e0 + w * 16 + (ln >> 2);
    if (er >= N_EDGES) er = N_EDGES - 1;
    int p0 = pairs[er];
    int p1 = pairs[N_EDGES + er];
    int qs = (ln & 3) ^ ((ln >> 3) & 3);
    const unsigned short* a0src = hbf + (size_t)p0 * DIN_ + qs * 8;
    const unsigned short* a1src = hbf + (size_t)p1 * DIN_ + qs * 8;
    int brow = w * 64;
    int swz = ((ln >> 4) ^ ((l15 >> 1) & 3)) * 8;

    // register-path staging of kk=8 (degrees + zero pad), swizzled ds_write
    int r8 = tid >> 2, q8 = tid & 3;
    int m8 = (q8 ^ ((r8 >> 1) & 3)) * 8;
    int ec8 = e0 + r8;
    if (ec8 >= N_EDGES) ec8 = N_EDGES - 1;

    f32x4 acc0[16], acc1[16];
#pragma unroll
    for (int j = 0; j < 16; ++j) { acc0[j] = (f32x4)(0.f); acc1[j] = (f32x4)(0.f); }

    // prologue: stage kk=0 into buf 0
    gl_lds16(a0src, &Alds[0][0][w * 16][0]);
    gl_lds16(a1src, &Alds[0][1][w * 16][0]);
#pragma unroll
    for (int i = 0; i < 4; ++i) {
        int n = brow + i * 16 + (ln >> 2);
        gl_lds16(WT + (size_t)n * KF_ + qs * 8, &Blds[0][brow + i * 16][0]);
    }
    __syncthreads();

    int buf = 0;
    for (int kk = 0; kk < 9; ++kk) {
        if (kk < 8) {
            // stage B for kk+1 (rows 256..287 of WT are the degree cols + zeros)
#pragma unroll
            for (int i = 0; i < 4; ++i) {
                int n = brow + i * 16 + (ln >> 2);
                gl_lds16(WT + (size_t)n * KF_ + (kk + 1) * 32 + qs * 8,
                         &Blds[buf ^ 1][brow + i * 16][0]);
            }
            if (kk < 7) {
                gl_lds16(a0src + (kk + 1) * 32, &Alds[buf ^ 1][0][w * 16][0]);
                gl_lds16(a1src + (kk + 1) * 32, &Alds[buf ^ 1][1][w * 16][0]);
            } else {
                // kk+1 == 8: degrees (k 256..271) + zeros (272..287), register path
#pragma unroll
                for (int t = 0; t < 2; ++t) {
                    uint4 v = make_uint4(0u, 0u, 0u, 0u);
                    if (q8 < 2) {
                        const float4* s4 = (const float4*)(degrees +
                            ((size_t)t * N_EDGES + ec8) * OH_ + q8 * 8);
                        float4 a = s4[0], b = s4[1];
                        v = pack8(a.x, a.y, a.z, a.w, b.x, b.y, b.z, b.w);
                    }
                    *(uint4*)&Alds[buf ^ 1][t][r8][m8] = v;
                }
            }
        }
        short8 a0f = *(const short8*)&Alds[buf][0][w * 16 + l15][swz];
        short8 a1f = *(const short8*)&Alds[buf][1][w * 16 + l15][swz];
#pragma unroll
        for (int j = 0; j < 16; ++j) {
            short8 bf = *(const short8*)&Blds[buf][j * 16 + l15][swz];
            acc0[j] = __builtin_amdgcn_mfma_f32_16x16x32_bf16(a0f, bf, acc0[j], 0, 0, 0);
            acc1[j] = __builtin_amdgcn_mfma_f32_16x16x32_bf16(a1f, bf, acc1[j], 0, 0, 0);
        }
        __syncthreads();
        buf ^= 1;
    }

    float epv = 1.0f + eps[0];
    int rloc = w * 16 + ((ln >> 4) << 2);
    int srow[4];
#pragma unroll
    for (int i = 0; i < 4; ++i) {
        int ee = e0 + rloc + i;
        srow[i] = scatter[ee < N_EDGES ? ee : N_EDGES - 1];
    }
#pragma unroll
    for (int j = 0; j < 16; ++j) {
        int n = j * 16 + l15;
        float bv = bias_lds[n];
#pragma unroll
        for (int i = 0; i < 4; ++i) {
            int ee = e0 + rloc + i;
            if (ee < N_EDGES) {
                float s0 = 1.0f / (1.0f + __expf(-(acc0[j][i] + bv)));
                float s1 = 1.0f / (1.0f + __expf(-(acc1[j][i] + bv)));
                atomicAdd(&out[(size_t)srow[i] * DOUT_ + n], epv * s0 * s1);
            }
        }
    }
}

extern "C" void kernel_launch(void* const* d_in, const int* in_sizes, int n_in,
                              void* d_out, int out_size, void* d_ws, size_t ws_size,
                              hipStream_t stream) {
    const float* h        = (const float*)d_in[0];
    const int*   pairs_k0 = (const int*)d_in[1];
    const int*   pairs_k1 = (const int*)d_in[2];
    const float* deg_k0   = (const float*)d_in[3];
    const float* deg_k1   = (const float*)d_in[4];
    const int*   sc_k0    = (const int*)d_in[5];
    const int*   sc_k1    = (const int*)d_in[6];
    const float* W_lin    = (const float*)d_in[7];
    const float* b_lin    = (const float*)d_in[8];
    const float* W_k0     = (const float*)d_in[9];
    const float* b_k0     = (const float*)d_in[10];
    const float* W_k1     = (const float*)d_in[11];
    const float* b_k1     = (const float*)d_in[12];
    const float* eps_k0   = (const float*)d_in[13];
    const float* eps_k1   = (const float*)d_in[14];
    float* out = (float*)d_out;

    size_t wt_elems = (size_t)DOUT_ * DIN_ + 2 * (size_t)DOUT_ * KF_;
    size_t need = (wt_elems + (size_t)N_NODES * DIN_) * sizeof(unsigned short);
    if (ws_size < need) return;  // workspace too small — fail loudly in validation
    unsigned short* WT_lin = (unsigned short*)d_ws;
    unsigned short* WT_k0  = WT_lin + DOUT_ * DIN_;
    unsigned short* WT_k1  = WT_k0 + DOUT_ * KF_;
    unsigned short* h_bf   = WT_k1 + DOUT_ * KF_;

    prep_weights<<<(DOUT_ * KF_ + 255) / 256, 256, 0, stream>>>(W_lin, W_k0, W_k1,
                                                                WT_lin, WT_k0, WT_k1);
    conv_h<<<(N_NODES * DIN_ / 8) / 256, 256, 0, stream>>>(h, h_bf);
    main_gemm<<<(N_NODES + 63) / 64, 256, 0, stream>>>(h_bf, WT_lin, b_lin, out);
    edge_gemm<<<(N_EDGES + 63) / 64, 256, 0, stream>>>(h_bf, pairs_k0, deg_k0, sc_k0,
                                                       WT_k0, b_k0, eps_k0, out);
    edge_gemm<<<(N_EDGES + 63) / 64, 256, 0, stream>>>(h_bf, pairs_k1, deg_k1, sc_k1,
                                                       WT_k1, b_k1, eps_k1, out);
}